// Round 2
// baseline (303.653 us; speedup 1.0000x reference)
//
#include <hip/hip_runtime.h>
#include <hip/hip_bf16.h>

#define S_TOK 8192
#define NEXP 64
#define MDIM 1024
#define CAP 128
#define NCH 512
#define CHUNK 16   // tokens per gate block
#define TPW 4      // tokens per wave
#define NFILL 1536 // fill blocks appended after the 512 gate blocks

// flat output offsets (all fp32 elements)
#define OFF2 67108865    // dispatch_mask start  (1 + 8192*64*128)
#define OFF3 134217729   // mask1 start
#define OFF4 134742017   // exp_counts start
#define OFF5 134742081   // indices1_s start
#define FILL4_END 33685504   // (OFF4-1)/4 ; float4 slots j in [1, FILL4_END) cover elements [4, OFF4)

// Kernel 1: blocks [0,512) compute the gate (logits GEMM + softmax + argmax +
// per-chunk ranks); blocks [512, 512+NFILL) stream-zero the huge output region.
// Disjoint memory -> safe concurrency, and the gate work hides under the fill's
// store stream instead of serializing after it.
__global__ __launch_bounds__(256) void gate_fill_kernel(
    const float* __restrict__ x, const float* __restrict__ wg,
    int* __restrict__ ind, int* __restrict__ rnk, float* __restrict__ gval,
    int* __restrict__ counts, float* __restrict__ gparts,
    float* __restrict__ out)
{
  const int b = blockIdx.x;
  if (b >= NCH) {
    // ---- pure streaming zero-fill of out[1 .. OFF4) ----
    const int tid = (b - NCH) * 256 + threadIdx.x;
    const int stride = NFILL * 256;
    if (tid == 0) { out[1] = 0.f; out[2] = 0.f; out[3] = 0.f; }
    const float4 z = make_float4(0.f, 0.f, 0.f, 0.f);
    for (int j = 1 + tid; j < FILL4_END; j += stride)
      *reinterpret_cast<float4*>(out + ((size_t)j << 2)) = z;
    return;
  }

  // ---- gate path ----
  __shared__ float s_gsum[4][64];
  __shared__ int s_ind[CHUNK];
  const int lane = threadIdx.x & 63;   // expert
  const int wv = threadIdx.x >> 6;     // wave 0..3
  const int tok0 = b * CHUNK + wv * TPW;

  float acc[TPW] = {0.f, 0.f, 0.f, 0.f};
  for (int d = 0; d < MDIM; d += 4) {
    const float w0 = wg[(d + 0) * NEXP + lane];
    const float w1 = wg[(d + 1) * NEXP + lane];
    const float w2 = wg[(d + 2) * NEXP + lane];
    const float w3 = wg[(d + 3) * NEXP + lane];
#pragma unroll
    for (int t = 0; t < TPW; ++t) {
      const float4 xv = *reinterpret_cast<const float4*>(x + (tok0 + t) * MDIM + d);
      acc[t] = fmaf(xv.x, w0, acc[t]);
      acc[t] = fmaf(xv.y, w1, acc[t]);
      acc[t] = fmaf(xv.z, w2, acc[t]);
      acc[t] = fmaf(xv.w, w3, acc[t]);
    }
  }

  float colsum = 0.f;
#pragma unroll
  for (int t = 0; t < TPW; ++t) {
    const float logit = acc[t];
    float m = logit;
#pragma unroll
    for (int off = 32; off > 0; off >>= 1) m = fmaxf(m, __shfl_xor(m, off, 64));
    const float ex = __expf(logit - m);
    float sm = ex;
#pragma unroll
    for (int off = 32; off > 0; off >>= 1) sm += __shfl_xor(sm, off, 64);
    colsum += ex / sm;                 // this lane's gate for this token
    const unsigned long long bal = __ballot(logit == m);
    const int widx = (int)(__ffsll(bal) - 1);   // lowest max lane == argmax tie-break
    if (lane == 0) {
      const int tk = tok0 + t;
      ind[tk] = widx;
      gval[tk] = 1.0f / sm;            // winning gate = exp(0)/sum
      s_ind[wv * TPW + t] = widx;
    }
  }
  s_gsum[wv][lane] = colsum;
  __syncthreads();
  if (wv == 0) {
    const float g = s_gsum[0][lane] + s_gsum[1][lane] + s_gsum[2][lane] + s_gsum[3][lane];
    gparts[b * NEXP + lane] = g;
    int cnt = 0;                       // deterministic within-chunk rank
#pragma unroll
    for (int t = 0; t < CHUNK; ++t) {
      const int e = s_ind[t];
      const int r = __shfl(cnt, e, 64);
      if (lane == 0) rnk[b * CHUNK + t] = r;
      cnt += (lane == e) ? 1 : 0;
    }
    counts[b * NEXP + lane] = cnt;
  }
}

// Kernel 2: 4-way parallel per-expert prefix over the 512 chunk counts,
// + exp_counts + l_aux. 256 threads = 4 groups x 64 experts.
__global__ __launch_bounds__(256) void reduce_kernel(
    const int* __restrict__ counts, const float* __restrict__ gparts,
    int* __restrict__ offs, float* __restrict__ out)
{
  __shared__ int s_cnt[4][64];
  __shared__ float s_gs[4][64];
  const int e = threadIdx.x & 63;
  const int g = threadIdx.x >> 6;      // chunk group: 128 chunks each
  const int ch0 = g * 128;

  int csum = 0; float gsum = 0.f;
#pragma unroll 8
  for (int ch = ch0; ch < ch0 + 128; ++ch) {
    csum += counts[ch * NEXP + e];
    gsum += gparts[ch * NEXP + e];
  }
  s_cnt[g][e] = csum; s_gs[g][e] = gsum;
  __syncthreads();

  int base = 0;
  for (int k = 0; k < g; ++k) base += s_cnt[k][e];
  int run = base;
#pragma unroll 8
  for (int ch = ch0; ch < ch0 + 128; ++ch) {
    offs[ch * NEXP + e] = run;         // exclusive prefix per expert
    run += counts[ch * NEXP + e];
  }
  if (g == 3) {
    const int total = run;             // full per-expert count
    out[OFF4 + e] = (float)total;
    const float gtot = s_gs[0][e] + s_gs[1][e] + s_gs[2][e] + s_gs[3][e];
    const float me = gtot * (1.0f / (float)S_TOK);
    const float ce = (float)total * (1.0f / (float)S_TOK);
    float prod = me * ce;
#pragma unroll
    for (int off = 32; off > 0; off >>= 1) prod += __shfl_xor(prod, off, 64);
    if (e == 0) out[0] = prod * (float)NEXP;   // l_aux
  }
}

// Kernel 3: per-token location + scatter of all nonzeros into the zeroed field.
__global__ __launch_bounds__(256) void scatter_kernel(
    const int* __restrict__ ind, const int* __restrict__ rnk,
    const int* __restrict__ offs, const float* __restrict__ gval,
    float* __restrict__ out)
{
  const int s = blockIdx.x * blockDim.x + threadIdx.x;
  if (s >= S_TOK) return;
  const int e = ind[s];
  const int loc = offs[(s >> 4) * NEXP + e] + rnk[s];
  out[OFF5 + s] = (float)e;                       // indices1_s
  out[OFF3 + (s << 6) + e] = 1.0f;                // mask1
  if (loc < CAP) {
    const size_t idx = ((size_t)s << 13) + (e << 7) + loc;
    out[1 + idx] = gval[s];                       // combine_weights
    out[OFF2 + idx] = 1.0f;                       // dispatch_mask
  }
}

extern "C" void kernel_launch(void* const* d_in, const int* in_sizes, int n_in,
                              void* d_out, int out_size, void* d_ws, size_t ws_size,
                              hipStream_t stream)
{
  const float* x = (const float*)d_in[0];
  const float* wg = (const float*)d_in[1];
  float* out = (float*)d_out;

  int* ind = (int*)d_ws;                          // 8192
  int* rnk = ind + S_TOK;                         // 8192
  float* gval = (float*)(rnk + S_TOK);            // 8192
  int* counts = (int*)(gval + S_TOK);             // 512*64
  float* gparts = (float*)(counts + NCH * NEXP);  // 512*64
  int* offs = (int*)(gparts + NCH * NEXP);        // 512*64

  gate_fill_kernel<<<NCH + NFILL, 256, 0, stream>>>(x, wg, ind, rnk, gval, counts, gparts, out);
  reduce_kernel<<<1, 256, 0, stream>>>(counts, gparts, offs, out);
  scatter_kernel<<<(S_TOK + 255) / 256, 256, 0, stream>>>(ind, rnk, offs, gval, out);
}

// Round 3
// 198.671 us; speedup vs baseline: 1.5284x; 1.5284x over previous
//
#include <hip/hip_runtime.h>
#include <hip/hip_bf16.h>

#define S_TOK 8192
#define NEXP 64
#define MDIM 1024
#define CAP 128
#define NCH 512
#define CHUNK 16   // tokens per gate block
#define TPW 4      // tokens per wave
#define SENT (-(1 << 30))

// flat output element offsets (fp32)
#define OFF2 67108865    // dispatch_mask start  (1 + 8192*64*128)
#define OFF3 134217729   // mask1 start
#define OFF4 134742017   // exp_counts start
#define OFF5 134742081   // indices1_s start
// float4 slot j covers elements [4j, 4j+4). Slots [1, 33685504) cover [4, 134742016).
#define SLOT_D0 16777216     // crossing slot: combine last elem + dispatch head
#define SLOT_M0 33554432     // crossing slot: dispatch last elem + mask1 head
#define SLOT_END 33685504

// ---------------- Kernel 1: gate (logits GEMM + softmax + argmax + chunk ranks)
__global__ __launch_bounds__(256) void gate_kernel(
    const float* __restrict__ x, const float* __restrict__ wg,
    int* __restrict__ ind, int* __restrict__ rnk, float* __restrict__ gval,
    int* __restrict__ counts, float* __restrict__ gparts)
{
  __shared__ float s_gsum[4][64];
  __shared__ int s_ind[CHUNK];
  const int b = blockIdx.x;
  const int lane = threadIdx.x & 63;   // expert
  const int wv = threadIdx.x >> 6;     // wave 0..3
  const int tok0 = b * CHUNK + wv * TPW;

  float acc[TPW] = {0.f, 0.f, 0.f, 0.f};
#pragma unroll 2
  for (int d = 0; d < MDIM; d += 4) {
    const float w0 = wg[(d + 0) * NEXP + lane];
    const float w1 = wg[(d + 1) * NEXP + lane];
    const float w2 = wg[(d + 2) * NEXP + lane];
    const float w3 = wg[(d + 3) * NEXP + lane];
#pragma unroll
    for (int t = 0; t < TPW; ++t) {
      const float4 xv = *reinterpret_cast<const float4*>(x + (tok0 + t) * MDIM + d);
      acc[t] = fmaf(xv.x, w0, acc[t]);
      acc[t] = fmaf(xv.y, w1, acc[t]);
      acc[t] = fmaf(xv.z, w2, acc[t]);
      acc[t] = fmaf(xv.w, w3, acc[t]);
    }
  }

  float colsum = 0.f;
#pragma unroll
  for (int t = 0; t < TPW; ++t) {
    const float logit = acc[t];
    float m = logit;
#pragma unroll
    for (int off = 32; off > 0; off >>= 1) m = fmaxf(m, __shfl_xor(m, off, 64));
    const float ex = __expf(logit - m);
    float sm = ex;
#pragma unroll
    for (int off = 32; off > 0; off >>= 1) sm += __shfl_xor(sm, off, 64);
    colsum += ex / sm;                 // this lane's gate for this token
    const unsigned long long bal = __ballot(logit == m);
    const int widx = (int)(__ffsll(bal) - 1);   // lowest max lane == argmax tie-break
    if (lane == 0) {
      const int tk = tok0 + t;
      ind[tk] = widx;
      gval[tk] = 1.0f / sm;            // winning gate = exp(0)/sum
      s_ind[wv * TPW + t] = widx;
    }
  }
  s_gsum[wv][lane] = colsum;
  __syncthreads();
  if (wv == 0) {
    const float g = s_gsum[0][lane] + s_gsum[1][lane] + s_gsum[2][lane] + s_gsum[3][lane];
    gparts[b * NEXP + lane] = g;
    int cnt = 0;                       // deterministic within-chunk rank
#pragma unroll
    for (int t = 0; t < CHUNK; ++t) {
      const int e = s_ind[t];
      const int r = __shfl(cnt, e, 64);
      if (lane == 0) rnk[b * CHUNK + t] = r;
      cnt += (lane == e) ? 1 : 0;
    }
    counts[b * NEXP + lane] = cnt;
  }
}

// ---------------- Kernel 2: 4-way parallel per-expert prefix + exp_counts + l_aux
__global__ __launch_bounds__(256) void reduce_kernel(
    const int* __restrict__ counts, const float* __restrict__ gparts,
    int* __restrict__ offs, float* __restrict__ out)
{
  __shared__ int s_cnt[4][64];
  __shared__ float s_gs[4][64];
  const int e = threadIdx.x & 63;
  const int g = threadIdx.x >> 6;      // chunk group: 128 chunks each
  const int ch0 = g * 128;

  int csum = 0; float gsum = 0.f;
#pragma unroll 8
  for (int ch = ch0; ch < ch0 + 128; ++ch) {
    csum += counts[ch * NEXP + e];
    gsum += gparts[ch * NEXP + e];
  }
  s_cnt[g][e] = csum; s_gs[g][e] = gsum;
  __syncthreads();

  int base = 0;
  for (int k = 0; k < g; ++k) base += s_cnt[k][e];
  int run = base;
#pragma unroll 8
  for (int ch = ch0; ch < ch0 + 128; ++ch) {
    offs[ch * NEXP + e] = run;         // exclusive prefix per expert
    run += counts[ch * NEXP + e];
  }
  if (g == 3) {
    const int total = run;
    out[OFF4 + e] = (float)total;
    const float gtot = s_gs[0][e] + s_gs[1][e] + s_gs[2][e] + s_gs[3][e];
    const float me = gtot * (1.0f / (float)S_TOK);
    const float ce = (float)total * (1.0f / (float)S_TOK);
    float prod = me * ce;
#pragma unroll
    for (int off = 32; off > 0; off >>= 1) prod += __shfl_xor(prod, off, 64);
    if (e == 0) out[0] = prod * (float)NEXP;   // l_aux
  }
}

// ---------------- Kernel 3: per-token nonzero position + specials (head/tail/crossing)
__global__ __launch_bounds__(256) void loc_kernel(
    const int* __restrict__ ind, const int* __restrict__ rnk,
    const int* __restrict__ offs, const float* __restrict__ gval,
    int* __restrict__ pos_c, float* __restrict__ out)
{
  const int s = blockIdx.x * 256 + threadIdx.x;
  if (s >= S_TOK) return;
  const int e = ind[s];
  const int loc = offs[(s >> 4) * NEXP + e] + rnk[s];
  const bool ok = (loc < CAP);
  const int rel = (s << 13) + (e << 7) + loc;   // s*8192 + e*128 + loc
  pos_c[s] = ok ? (1 + rel) : SENT;             // combine elem index; dispatch = +OFF2-1
  const float gv = gval[s];
  out[OFF5 + s] = (float)e;                     // indices1_s

  if (s == 0) {
    // head elements 1..3 (combine token0 ec 0..2)
    out[1] = (ok && rel == 0) ? gv : 0.f;
    out[2] = (ok && rel == 1) ? gv : 0.f;
    out[3] = (ok && rel == 2) ? gv : 0.f;
    // crossing slot SLOT_D0 tail part: dispatch idx 0..2
    out[OFF2 + 0] = (ok && rel == 0) ? 1.f : 0.f;
    out[OFF2 + 1] = (ok && rel == 1) ? 1.f : 0.f;
    out[OFF2 + 2] = (ok && rel == 2) ? 1.f : 0.f;
    // crossing slot SLOT_M0 tail part: mask1 idx 0..2
    out[OFF3 + 0] = (e == 0) ? 1.f : 0.f;
    out[OFF3 + 1] = (e == 1) ? 1.f : 0.f;
    out[OFF3 + 2] = (e == 2) ? 1.f : 0.f;
  }
  if (s == S_TOK - 1) {
    // combine last element (token 8191, ec 8191) = element 4*SLOT_D0
    out[67108864]  = (ok && rel == 67108863) ? gv : 0.f;
    // dispatch last element = element 4*SLOT_M0
    out[134217728] = (ok && rel == 67108863) ? 1.f : 0.f;
    // mask1 last element (tail, element OFF4-1)
    out[OFF4 - 1]  = (e == 63) ? 1.f : 0.f;
  }
}

// ---------------- Kernel 4: pure-store fill of combine/dispatch/mask1
// blocks [0,2048): combine, 4 token-spans each (slots [2048t, 2048t+2048))
// blocks [2048,4096): dispatch, same shape shifted by SLOT_D0
// blocks [4096,4224): mask1 interior slots [SLOT_M0+1, SLOT_END)
__global__ __launch_bounds__(256) void write_kernel(
    const int* __restrict__ pos_c, const float* __restrict__ gval,
    const int* __restrict__ ind, float* __restrict__ out)
{
  const int b = blockIdx.x;
  const int tid = threadIdx.x;
  if (b < 4096) {
    const bool isC = (b < 2048);
    const int bb = isC ? b : b - 2048;
    const int sbase = isC ? 0 : SLOT_D0;
    const int pshift = isC ? 0 : (OFF2 - 1);
#pragma unroll
    for (int si = 0; si < 4; ++si) {
      const int t = bb * 4 + si;                 // token span
      const int s0 = sbase + t * 2048;           // first slot of slab
      const int p1 = pos_c[t] + pshift;          // this token's nonzero element (or SENT-ish)
      const float v1 = isC ? gval[t] : 1.0f;
      const int p0 = (t > 0) ? (pos_c[t - 1] + pshift) : SENT;
      const float v0 = (t > 0) ? (isC ? gval[t - 1] : 1.0f) : 0.0f;
#pragma unroll
      for (int k = 0; k < 8; ++k) {
        const int j = s0 + k * 256 + tid;
        if (t == 0 && k == 0 && tid == 0) continue;   // head / crossing slot
        const int g0 = j << 2;
        const int d = p1 - g0;
        float4 v;
        v.x = (d == 0) ? v1 : 0.0f;
        v.y = (d == 1) ? v1 : 0.0f;
        v.z = (d == 2) ? v1 : 0.0f;
        v.w = (d == 3) ? v1 : 0.0f;
        if (j == s0 && p0 == g0) v.x = v0;            // prev token's last element
        *reinterpret_cast<float4*>(out + (size_t)g0) = v;
      }
    }
  } else {
    const int u = b - 4096;
#pragma unroll
    for (int k = 0; k < 4; ++k) {
      const int j = SLOT_M0 + 1 + u * 1024 + k * 256 + tid;
      if (j >= SLOT_END) return;
      const int g0 = j << 2;
      const int m0 = g0 - OFF3;
      float4 v;
      v.x = (ind[(m0 + 0) >> 6] == ((m0 + 0) & 63)) ? 1.f : 0.f;
      v.y = (ind[(m0 + 1) >> 6] == ((m0 + 1) & 63)) ? 1.f : 0.f;
      v.z = (ind[(m0 + 2) >> 6] == ((m0 + 2) & 63)) ? 1.f : 0.f;
      v.w = (ind[(m0 + 3) >> 6] == ((m0 + 3) & 63)) ? 1.f : 0.f;
      *reinterpret_cast<float4*>(out + (size_t)g0) = v;
    }
  }
}

extern "C" void kernel_launch(void* const* d_in, const int* in_sizes, int n_in,
                              void* d_out, int out_size, void* d_ws, size_t ws_size,
                              hipStream_t stream)
{
  const float* x = (const float*)d_in[0];
  const float* wg = (const float*)d_in[1];
  float* out = (float*)d_out;

  int* ind = (int*)d_ws;                          // 8192
  int* rnk = ind + S_TOK;                         // 8192
  float* gval = (float*)(rnk + S_TOK);            // 8192
  int* pos_c = (int*)(gval + S_TOK);              // 8192
  int* counts = pos_c + S_TOK;                    // 512*64
  float* gparts = (float*)(counts + NCH * NEXP);  // 512*64
  int* offs = (int*)(gparts + NCH * NEXP);        // 512*64

  gate_kernel<<<NCH, 256, 0, stream>>>(x, wg, ind, rnk, gval, counts, gparts);
  reduce_kernel<<<1, 256, 0, stream>>>(counts, gparts, offs, out);
  loc_kernel<<<S_TOK / 256, 256, 0, stream>>>(ind, rnk, offs, gval, pos_c, out);
  write_kernel<<<4224, 256, 0, stream>>>(pos_c, gval, ind, out);
}